// Round 9
// baseline (115.309 us; speedup 1.0000x reference)
//
#include <hip/hip_runtime.h>
#include <hip/hip_bf16.h>
#include <math.h>

#define T_DIM 4096
#define D_DIM 64
#define SPLITS 8
#define SCALE_X 14.4269504088896340736f   // (1/TEMPERATURE) * log2(e): exp(10 s) = exp2(14.427 s)
#define LN2 0.69314718055994530942f

typedef short bfrag8 __attribute__((ext_vector_type(8)));   // 8 bf16 = 4 VGPRs
typedef float floatx4 __attribute__((ext_vector_type(4)));

__device__ __forceinline__ float bf2f(unsigned short u) {
    return __uint_as_float(((unsigned int)u) << 16);
}

// ---------------------------------------------------------------------------
// K1 "prep": fused normalize (blocks [0,normBlocks)) + parallel 2-pass mask
// compaction + gsum/out zeroing (blocks [normBlocks, normBlocks+2B)).
// Normalize: 16 rows/block, 16 lanes/row, float4 loads, ushort4 stores;
// rows with combined mask 0 are SKIPPED (main clamps all reads to selected
// rows, so poison in unselected rows is never read).
// x rows scaled by SCALE_X (folds 1/T and log2(e) into the bf16 cast).
// ---------------------------------------------------------------------------
__launch_bounds__(256)
__global__ void prep(const float* __restrict__ x, const float* __restrict__ y,
                     const int* __restrict__ im1, const int* __restrict__ sh1,
                     const int* __restrict__ im2, const int* __restrict__ sh2,
                     __hip_bfloat16* __restrict__ xn, __hip_bfloat16* __restrict__ yn,
                     int* __restrict__ Ridx, int* __restrict__ Cidx,
                     int* __restrict__ cnt, float* __restrict__ gsum,
                     float* __restrict__ out,
                     int rows, int normBlocks, int B) {
    int tid = threadIdx.x;
    if ((int)blockIdx.x < normBlocks) {
        int row = blockIdx.x * 16 + (tid >> 4);
        int l = tid & 15;
        const float* src; __hip_bfloat16* dst; float scale; int sel;
        if (row < rows) {
            src = x; dst = xn; scale = SCALE_X;
            sel = im1[row] * sh1[row];
        } else {
            row -= rows;
            src = y; dst = yn; scale = 1.0f;
            sel = im2[row] * sh2[row];
        }
        if (!sel) return;   // whole 16-lane group exits together
        size_t off = (size_t)row * D_DIM + l * 4;
        float4 v = *reinterpret_cast<const float4*>(src + off);
        float ss = v.x * v.x + v.y * v.y + v.z * v.z + v.w * v.w;
        #pragma unroll
        for (int o = 1; o < 16; o <<= 1) ss += __shfl_xor(ss, o);
        float inv = scale / fmaxf(sqrtf(ss), 1e-12f);
        __hip_bfloat16 h0 = __float2bfloat16(v.x * inv);
        __hip_bfloat16 h1 = __float2bfloat16(v.y * inv);
        __hip_bfloat16 h2 = __float2bfloat16(v.z * inv);
        __hip_bfloat16 h3 = __float2bfloat16(v.w * inv);
        ushort4 o4;
        o4.x = *reinterpret_cast<unsigned short*>(&h0);
        o4.y = *reinterpret_cast<unsigned short*>(&h1);
        o4.z = *reinterpret_cast<unsigned short*>(&h2);
        o4.w = *reinterpret_cast<unsigned short*>(&h3);
        *reinterpret_cast<ushort4*>((unsigned short*)dst + off) = o4;
    } else {
        int z = blockIdx.x - normBlocks;
        int which = z & 1, b = z >> 1;
        const int* im = which ? im2 : im1;
        const int* sh = which ? sh2 : sh1;
        int* idxout   = which ? Cidx : Ridx;

        // 64 wave-units of 64 elements; wave w owns units w, w+4, ..., w+60.
        __shared__ int cw[64];     // per-unit selected count
        __shared__ int offx[64];   // exclusive prefix
        int w = tid >> 6, lane = tid & 63;
        const int* imb = im + (size_t)b * T_DIM;
        const int* shb = sh + (size_t)b * T_DIM;

        // pass 1: parallel counts
        #pragma unroll
        for (int k = 0; k < 16; k++) {
            int u = w + k * 4;
            int t = u * 64 + lane;
            int mv = imb[t] * shb[t];
            unsigned long long bal = __ballot(mv != 0);
            if (lane == 0) cw[u] = __popcll(bal);
        }
        __syncthreads();
        // scan 64 counts on wave 0
        if (w == 0) {
            int v = cw[lane];
            int incl = v;
            #pragma unroll
            for (int o = 1; o < 64; o <<= 1) {
                int t = __shfl_up(incl, o);
                if (lane >= o) incl += t;
            }
            offx[lane] = incl - v;
            if (lane == 63) cnt[which * B + b] = incl;
        }
        __syncthreads();
        // pass 2: parallel writes
        #pragma unroll
        for (int k = 0; k < 16; k++) {
            int u = w + k * 4;
            int t = u * 64 + lane;
            int mv = imb[t] * shb[t];
            unsigned long long bal = __ballot(mv != 0);
            int pre = __popcll(bal & ((1ull << lane) - 1ull));
            if (mv) idxout[(size_t)b * T_DIM + offx[u] + pre] = t;
        }
        // zero gsum for this batch + out
        if (which == 0) {
            for (int i = tid; i < T_DIM; i += 256) gsum[(size_t)b * T_DIM + i] = 0.0f;
            if (b == 0 && tid == 0) out[0] = 0.0f;
        }
    }
}

// ---------------------------------------------------------------------------
// K2 main: grid (T/64 col-tiles, B, SPLITS); 256 thr / 4 waves — the
// measured-best split-K structure (r5: 108.4 us). Gathers selected rows via
// Ridx: gsum[c] += sum_{i<nx} exp2(sim2[R_i][c]), sim2 in log2 units.
// Tail indices CLAMPED to last selected row/col (mask-skip prep leaves
// unselected rows poisoned). Two-level prefetch; direct gsum atomics.
// ---------------------------------------------------------------------------
__launch_bounds__(256)
__global__ void ntxent_main(const __hip_bfloat16* __restrict__ xn,
                            const __hip_bfloat16* __restrict__ yn,
                            const int* __restrict__ Ridx,
                            const int* __restrict__ Cidx,
                            const int* __restrict__ cnt,
                            float* __restrict__ gsum, int B) {
    int b  = blockIdx.y;
    int nx = cnt[b];
    int ny = cnt[B + b];
    int m  = min(nx, ny);
    int j0 = blockIdx.x * 64;
    if (j0 >= m) return;
    int rbase = blockIdx.z * 64;          // row stride 64*SPLITS = 512 selected rows

    __shared__ __hip_bfloat16 Bs[64 * 72];   // col-vector stride 144B
    __shared__ int Cloc[64];

    int tid  = threadIdx.x;
    int wave = tid >> 6, lane = tid & 63, quad = lane >> 4, c16 = lane & 15;

    if (tid < 64) {
        int j = min(j0 + tid, ny - 1);    // clamp: only selected cols are read
        Cloc[tid] = Cidx[(size_t)b * T_DIM + j];
    }
    __syncthreads();

    // Stage B tile: 64 col vectors x 128B
    #pragma unroll
    for (int i = tid; i < 64 * 8; i += 256) {
        int c = i >> 3, part = i & 7;
        bfrag8 v = *reinterpret_cast<const bfrag8*>(
            yn + ((size_t)b * T_DIM + Cloc[c]) * D_DIM + part * 8);
        *reinterpret_cast<bfrag8*>(&Bs[c * 72 + part * 8]) = v;
    }
    __syncthreads();

    bfrag8 bf[4][2];
    #pragma unroll
    for (int cg = 0; cg < 4; cg++)
        #pragma unroll
        for (int kh = 0; kh < 2; kh++)
            bf[cg][kh] = *reinterpret_cast<const bfrag8*>(
                &Bs[(cg * 16 + c16) * 72 + kh * 32 + quad * 8]);

    const __hip_bfloat16* xb = xn + (size_t)b * T_DIM * D_DIM;
    const int* Rb = Ridx + (size_t)b * T_DIM;

    float csum[4] = {0.f, 0.f, 0.f, 0.f};

    // prefetch iter 0 (tail indices clamped to Rb[nx-1]: valid, normalized)
    int gi = rbase + wave * 16 + c16;
    int idx0 = Rb[min(gi, nx - 1)];
    const __hip_bfloat16* arow = xb + (size_t)idx0 * D_DIM;
    bfrag8 af0 = *reinterpret_cast<const bfrag8*>(arow + quad * 8);
    bfrag8 af1 = *reinterpret_cast<const bfrag8*>(arow + 32 + quad * 8);

    for (int i0 = rbase; i0 < nx; i0 += 64 * SPLITS) {
        int gin = i0 + 64 * SPLITS + wave * 16 + c16;
        int idxn = Rb[min(gin, nx - 1)];
        const __hip_bfloat16* narow = xb + (size_t)idxn * D_DIM;
        bfrag8 naf0 = *reinterpret_cast<const bfrag8*>(narow + quad * 8);
        bfrag8 naf1 = *reinterpret_cast<const bfrag8*>(narow + 32 + quad * 8);

        int grow0 = i0 + wave * 16 + quad * 4;
        float wv[4];
        #pragma unroll
        for (int r = 0; r < 4; r++) wv[r] = (grow0 + r < nx) ? 1.0f : 0.0f;

        #pragma unroll
        for (int cg = 0; cg < 4; cg++) {
            floatx4 acc = {0.f, 0.f, 0.f, 0.f};
            acc = __builtin_amdgcn_mfma_f32_16x16x32_bf16(af0, bf[cg][0], acc, 0, 0, 0);
            acc = __builtin_amdgcn_mfma_f32_16x16x32_bf16(af1, bf[cg][1], acc, 0, 0, 0);
            #pragma unroll
            for (int r = 0; r < 4; r++)
                csum[cg] += wv[r] * exp2f(acc[r]);
        }
        af0 = naf0; af1 = naf1;
    }

    // reduce over quads (rows): lanes differing in bits 4,5 hold same column
    #pragma unroll
    for (int cg = 0; cg < 4; cg++) {
        csum[cg] += __shfl_xor(csum[cg], 16);
        csum[cg] += __shfl_xor(csum[cg], 32);
    }
    if (lane < 16) {
        #pragma unroll
        for (int cg = 0; cg < 4; cg++)
            atomicAdd(&gsum[(size_t)b * T_DIM + j0 + cg * 16 + c16], csum[cg]);
    }
}

// ---------------------------------------------------------------------------
// K3: per-column loss + final mean. One 16-lane group per column, no serial
// loop (2048 blocks): diag2 = dot(xn,yn) in log2 units, per = LN2*(log2(g)-d2).
// Block sum / (m*B) atomicAdd'ed into out[0] (zeroed in prep).
// ---------------------------------------------------------------------------
__launch_bounds__(256)
__global__ void per_col_loss(const __hip_bfloat16* __restrict__ xn,
                             const __hip_bfloat16* __restrict__ yn,
                             const float* __restrict__ gsum,
                             const int* __restrict__ Ridx, const int* __restrict__ Cidx,
                             const int* __restrict__ cnt,
                             float* __restrict__ out, int B) {
    int b  = blockIdx.y;
    int m  = min(cnt[b], cnt[B + b]);
    int j0 = blockIdx.x * 16;
    if (j0 >= m) return;

    int tid = threadIdx.x, wave = tid >> 6, lane = tid & 63;
    int g = tid >> 4, l = tid & 15;
    int j = j0 + g;

    float acc = 0.0f;
    if (j < m) {
        int rj = Ridx[(size_t)b * T_DIM + j];
        int cj = Cidx[(size_t)b * T_DIM + j];
        const unsigned short* xa =
            (const unsigned short*)(xn + ((size_t)b * T_DIM + rj) * D_DIM) + l * 4;
        const unsigned short* yc =
            (const unsigned short*)(yn + ((size_t)b * T_DIM + cj) * D_DIM) + l * 4;
        float d = 0.0f;
        #pragma unroll
        for (int e = 0; e < 4; e++) d += bf2f(xa[e]) * bf2f(yc[e]);
        #pragma unroll
        for (int o = 1; o < 16; o <<= 1) d += __shfl_xor(d, o);
        if (l == 0) acc = LN2 * (__log2f(gsum[(size_t)b * T_DIM + j]) - d);
    }
    #pragma unroll
    for (int o = 1; o < 64; o <<= 1) acc += __shfl_xor(acc, o);
    __shared__ float ws[4];
    if (lane == 0) ws[wave] = acc;
    __syncthreads();
    if (tid == 0)
        atomicAdd(out, (ws[0] + ws[1] + ws[2] + ws[3]) / ((float)m * (float)B));
}

extern "C" void kernel_launch(void* const* d_in, const int* in_sizes, int n_in,
                              void* d_out, int out_size, void* d_ws, size_t ws_size,
                              hipStream_t stream) {
    const float* x  = (const float*)d_in[0];
    const float* y  = (const float*)d_in[1];
    const int* im1  = (const int*)d_in[2];
    const int* im2  = (const int*)d_in[3];
    const int* sh1  = (const int*)d_in[4];
    const int* sh2  = (const int*)d_in[5];

    int B = in_sizes[2] / T_DIM;
    int rows = B * T_DIM;
    size_t nElem = (size_t)rows * D_DIM;

    __hip_bfloat16* xn = (__hip_bfloat16*)d_ws;
    __hip_bfloat16* yn = xn + nElem;
    float* gsum = (float*)(yn + nElem);     // B*T floats
    int*   Ridx = (int*)(gsum + rows);
    int*   Cidx = Ridx + rows;
    int*   cnt  = Cidx + rows;              // 2*B ints

    int normBlocks = 2 * rows / 16;
    prep<<<normBlocks + 2 * B, 256, 0, stream>>>(x, y, im1, sh1, im2, sh2,
                                                 xn, yn, Ridx, Cidx, cnt,
                                                 gsum, (float*)d_out,
                                                 rows, normBlocks, B);

    dim3 grid(T_DIM / 64, B, SPLITS);
    ntxent_main<<<grid, 256, 0, stream>>>(xn, yn, Ridx, Cidx, cnt, gsum, B);

    dim3 grid2(T_DIM / 16, B);
    per_col_loss<<<grid2, 256, 0, stream>>>(xn, yn, gsum, Ridx, Cidx, cnt,
                                            (float*)d_out, B);
}

// Round 10
// 107.888 us; speedup vs baseline: 1.0688x; 1.0688x over previous
//
#include <hip/hip_runtime.h>
#include <hip/hip_bf16.h>
#include <math.h>

#define T_DIM 4096
#define D_DIM 64
#define SPLITS 8
#define SCALE_X 14.4269504088896340736f   // (1/TEMPERATURE) * log2(e): exp(10 s) = exp2(14.427 s)
#define LN2 0.69314718055994530942f

typedef short bfrag8 __attribute__((ext_vector_type(8)));   // 8 bf16 = 4 VGPRs
typedef float floatx4 __attribute__((ext_vector_type(4)));

__device__ __forceinline__ float bf2f(unsigned short u) {
    return __uint_as_float(((unsigned int)u) << 16);
}

// ---------------------------------------------------------------------------
// K1 "prep": fused normalize (blocks [0,normBlocks)) + parallel 2-pass mask
// compaction + out zeroing (blocks [normBlocks, normBlocks+2B)).
// Normalize: 16 rows/block, 16 lanes/row, float4 loads, ushort4 stores.
// x rows scaled by SCALE_X (folds 1/T and log2(e) into the bf16 cast).
// NOTE (r9 post-mortem): do NOT mask-skip here — the dependent mask-load
// before the data load serializes two global latencies and measurably
// regresses. Unconditional normalize is faster despite 2x writes.
// ---------------------------------------------------------------------------
__launch_bounds__(256)
__global__ void prep(const float* __restrict__ x, const float* __restrict__ y,
                     const int* __restrict__ im1, const int* __restrict__ sh1,
                     const int* __restrict__ im2, const int* __restrict__ sh2,
                     __hip_bfloat16* __restrict__ xn, __hip_bfloat16* __restrict__ yn,
                     int* __restrict__ Ridx, int* __restrict__ Cidx,
                     int* __restrict__ cnt, float* __restrict__ gsum,
                     float* __restrict__ out,
                     int rows, int normBlocks, int B) {
    int tid = threadIdx.x;
    if ((int)blockIdx.x < normBlocks) {
        int row = blockIdx.x * 16 + (tid >> 4);
        int l = tid & 15;
        const float* src; __hip_bfloat16* dst; float scale;
        if (row < rows) { src = x; dst = xn; scale = SCALE_X; }
        else { src = y; dst = yn; scale = 1.0f; row -= rows; }
        size_t off = (size_t)row * D_DIM + l * 4;
        float4 v = *reinterpret_cast<const float4*>(src + off);
        float ss = v.x * v.x + v.y * v.y + v.z * v.z + v.w * v.w;
        #pragma unroll
        for (int o = 1; o < 16; o <<= 1) ss += __shfl_xor(ss, o);
        float inv = scale / fmaxf(sqrtf(ss), 1e-12f);
        __hip_bfloat16 h0 = __float2bfloat16(v.x * inv);
        __hip_bfloat16 h1 = __float2bfloat16(v.y * inv);
        __hip_bfloat16 h2 = __float2bfloat16(v.z * inv);
        __hip_bfloat16 h3 = __float2bfloat16(v.w * inv);
        ushort4 o4;
        o4.x = *reinterpret_cast<unsigned short*>(&h0);
        o4.y = *reinterpret_cast<unsigned short*>(&h1);
        o4.z = *reinterpret_cast<unsigned short*>(&h2);
        o4.w = *reinterpret_cast<unsigned short*>(&h3);
        *reinterpret_cast<ushort4*>((unsigned short*)dst + off) = o4;
    } else {
        int z = blockIdx.x - normBlocks;
        int which = z & 1, b = z >> 1;
        const int* im = which ? im2 : im1;
        const int* sh = which ? sh2 : sh1;
        int* idxout   = which ? Cidx : Ridx;

        // 64 wave-units of 64 elements; wave w owns units w, w+4, ..., w+60.
        __shared__ int cw[64];     // per-unit selected count
        __shared__ int offx[64];   // exclusive prefix
        int w = tid >> 6, lane = tid & 63;
        const int* imb = im + (size_t)b * T_DIM;
        const int* shb = sh + (size_t)b * T_DIM;

        // pass 1: parallel counts
        #pragma unroll
        for (int k = 0; k < 16; k++) {
            int u = w + k * 4;
            int t = u * 64 + lane;
            int mv = imb[t] * shb[t];
            unsigned long long bal = __ballot(mv != 0);
            if (lane == 0) cw[u] = __popcll(bal);
        }
        __syncthreads();
        // scan 64 counts on wave 0
        if (w == 0) {
            int v = cw[lane];
            int incl = v;
            #pragma unroll
            for (int o = 1; o < 64; o <<= 1) {
                int t = __shfl_up(incl, o);
                if (lane >= o) incl += t;
            }
            offx[lane] = incl - v;
            if (lane == 63) cnt[which * B + b] = incl;
        }
        __syncthreads();
        // pass 2: parallel writes
        #pragma unroll
        for (int k = 0; k < 16; k++) {
            int u = w + k * 4;
            int t = u * 64 + lane;
            int mv = imb[t] * shb[t];
            unsigned long long bal = __ballot(mv != 0);
            int pre = __popcll(bal & ((1ull << lane) - 1ull));
            if (mv) idxout[(size_t)b * T_DIM + offx[u] + pre] = t;
        }
        // zero gsum for this batch + out
        if (which == 0) {
            for (int i = tid; i < T_DIM; i += 256) gsum[(size_t)b * T_DIM + i] = 0.0f;
            if (b == 0 && tid == 0) out[0] = 0.0f;
        }
    }
}

// ---------------------------------------------------------------------------
// K2 main: grid (T/64 col-tiles, B, SPLITS); 256 thr / 4 waves — the
// measured-best split-K structure (r5: 108.4 us). Gathers selected rows via
// Ridx: gsum[c] += sum_{i<nx} exp2(sim2[R_i][c]), sim2 in log2 units
// (scale folded into xn). Two-level prefetch; tail rows use index 0 with
// weight 0 (all rows normalized by prep, so index 0 is always valid data).
// ---------------------------------------------------------------------------
__launch_bounds__(256)
__global__ void ntxent_main(const __hip_bfloat16* __restrict__ xn,
                            const __hip_bfloat16* __restrict__ yn,
                            const int* __restrict__ Ridx,
                            const int* __restrict__ Cidx,
                            const int* __restrict__ cnt,
                            float* __restrict__ gsum, int B) {
    int b  = blockIdx.y;
    int nx = cnt[b];
    int ny = cnt[B + b];
    int m  = min(nx, ny);
    int j0 = blockIdx.x * 64;
    if (j0 >= m) return;
    int rbase = blockIdx.z * 64;          // row stride 64*SPLITS = 512 selected rows

    __shared__ __hip_bfloat16 Bs[64 * 72];   // col-vector stride 144B
    __shared__ int Cloc[64];

    int tid  = threadIdx.x;
    int wave = tid >> 6, lane = tid & 63, quad = lane >> 4, c16 = lane & 15;

    if (tid < 64) {
        int j = j0 + tid;
        Cloc[tid] = (j < ny) ? Cidx[(size_t)b * T_DIM + j] : 0;
    }
    __syncthreads();

    // Stage B tile: 64 col vectors x 128B
    #pragma unroll
    for (int i = tid; i < 64 * 8; i += 256) {
        int c = i >> 3, part = i & 7;
        bfrag8 v = *reinterpret_cast<const bfrag8*>(
            yn + ((size_t)b * T_DIM + Cloc[c]) * D_DIM + part * 8);
        *reinterpret_cast<bfrag8*>(&Bs[c * 72 + part * 8]) = v;
    }
    __syncthreads();

    bfrag8 bf[4][2];
    #pragma unroll
    for (int cg = 0; cg < 4; cg++)
        #pragma unroll
        for (int kh = 0; kh < 2; kh++)
            bf[cg][kh] = *reinterpret_cast<const bfrag8*>(
                &Bs[(cg * 16 + c16) * 72 + kh * 32 + quad * 8]);

    const __hip_bfloat16* xb = xn + (size_t)b * T_DIM * D_DIM;
    const int* Rb = Ridx + (size_t)b * T_DIM;

    float csum[4] = {0.f, 0.f, 0.f, 0.f};

    // prefetch iter 0: index then row (tail rows use row 0, weight 0)
    int gi = rbase + wave * 16 + c16;
    int idx0 = (gi < nx) ? Rb[gi] : 0;
    const __hip_bfloat16* arow = xb + (size_t)idx0 * D_DIM;
    bfrag8 af0 = *reinterpret_cast<const bfrag8*>(arow + quad * 8);
    bfrag8 af1 = *reinterpret_cast<const bfrag8*>(arow + 32 + quad * 8);

    for (int i0 = rbase; i0 < nx; i0 += 64 * SPLITS) {
        int gin = i0 + 64 * SPLITS + wave * 16 + c16;
        int idxn = (gin < nx) ? Rb[gin] : 0;
        const __hip_bfloat16* narow = xb + (size_t)idxn * D_DIM;
        bfrag8 naf0 = *reinterpret_cast<const bfrag8*>(narow + quad * 8);
        bfrag8 naf1 = *reinterpret_cast<const bfrag8*>(narow + 32 + quad * 8);

        int grow0 = i0 + wave * 16 + quad * 4;
        float wv[4];
        #pragma unroll
        for (int r = 0; r < 4; r++) wv[r] = (grow0 + r < nx) ? 1.0f : 0.0f;

        #pragma unroll
        for (int cg = 0; cg < 4; cg++) {
            floatx4 acc = {0.f, 0.f, 0.f, 0.f};
            acc = __builtin_amdgcn_mfma_f32_16x16x32_bf16(af0, bf[cg][0], acc, 0, 0, 0);
            acc = __builtin_amdgcn_mfma_f32_16x16x32_bf16(af1, bf[cg][1], acc, 0, 0, 0);
            #pragma unroll
            for (int r = 0; r < 4; r++)
                csum[cg] += wv[r] * exp2f(acc[r]);
        }
        af0 = naf0; af1 = naf1;
    }

    // reduce over quads (rows): lanes differing in bits 4,5 hold same column
    #pragma unroll
    for (int cg = 0; cg < 4; cg++) {
        csum[cg] += __shfl_xor(csum[cg], 16);
        csum[cg] += __shfl_xor(csum[cg], 32);
    }
    if (lane < 16) {
        #pragma unroll
        for (int cg = 0; cg < 4; cg++)
            atomicAdd(&gsum[(size_t)b * T_DIM + j0 + cg * 16 + c16], csum[cg]);
    }
}

// ---------------------------------------------------------------------------
// K3: per-column loss + final mean. 16 blocks/batch; each 16-lane group does
// one column per round: diag2 = dot(xn,yn) (log2 units), per = LN2*(log2(g)-d2).
// Block sum / (m*B) atomicAdd'ed into out[0] (zeroed in prep).
// NOTE (r9 post-mortem): keep the 128-block loop form — the 2048-block
// no-loop variant regressed (dispatch ramp for mostly-idle blocks).
// ---------------------------------------------------------------------------
__launch_bounds__(256)
__global__ void per_col_loss(const __hip_bfloat16* __restrict__ xn,
                             const __hip_bfloat16* __restrict__ yn,
                             const float* __restrict__ gsum,
                             const int* __restrict__ Ridx, const int* __restrict__ Cidx,
                             const int* __restrict__ cnt,
                             float* __restrict__ out, int B) {
    int b  = blockIdx.y;
    int m  = min(cnt[b], cnt[B + b]);
    if (m <= 0) return;

    int tid = threadIdx.x, wave = tid >> 6, lane = tid & 63;
    int g = tid >> 4, l = tid & 15;

    float acc = 0.0f;
    for (int j = blockIdx.x * 16 + g; j < m; j += 16 * gridDim.x) {
        int rj = Ridx[(size_t)b * T_DIM + j];
        int cj = Cidx[(size_t)b * T_DIM + j];
        const unsigned short* xa =
            (const unsigned short*)(xn + ((size_t)b * T_DIM + rj) * D_DIM) + l * 4;
        const unsigned short* yc =
            (const unsigned short*)(yn + ((size_t)b * T_DIM + cj) * D_DIM) + l * 4;
        float d = 0.0f;
        #pragma unroll
        for (int e = 0; e < 4; e++) d += bf2f(xa[e]) * bf2f(yc[e]);
        #pragma unroll
        for (int o = 1; o < 16; o <<= 1) d += __shfl_xor(d, o);
        if (l == 0) acc += LN2 * (__log2f(gsum[(size_t)b * T_DIM + j]) - d);
    }
    #pragma unroll
    for (int o = 1; o < 64; o <<= 1) acc += __shfl_xor(acc, o);
    __shared__ float ws[4];
    if (lane == 0) ws[wave] = acc;
    __syncthreads();
    if (tid == 0)
        atomicAdd(out, (ws[0] + ws[1] + ws[2] + ws[3]) / ((float)m * (float)B));
}

extern "C" void kernel_launch(void* const* d_in, const int* in_sizes, int n_in,
                              void* d_out, int out_size, void* d_ws, size_t ws_size,
                              hipStream_t stream) {
    const float* x  = (const float*)d_in[0];
    const float* y  = (const float*)d_in[1];
    const int* im1  = (const int*)d_in[2];
    const int* im2  = (const int*)d_in[3];
    const int* sh1  = (const int*)d_in[4];
    const int* sh2  = (const int*)d_in[5];

    int B = in_sizes[2] / T_DIM;
    int rows = B * T_DIM;
    size_t nElem = (size_t)rows * D_DIM;

    __hip_bfloat16* xn = (__hip_bfloat16*)d_ws;
    __hip_bfloat16* yn = xn + nElem;
    float* gsum = (float*)(yn + nElem);     // B*T floats
    int*   Ridx = (int*)(gsum + rows);
    int*   Cidx = Ridx + rows;
    int*   cnt  = Cidx + rows;              // 2*B ints

    int normBlocks = 2 * rows / 16;
    prep<<<normBlocks + 2 * B, 256, 0, stream>>>(x, y, im1, sh1, im2, sh2,
                                                 xn, yn, Ridx, Cidx, cnt,
                                                 gsum, (float*)d_out,
                                                 rows, normBlocks, B);

    dim3 grid(T_DIM / 64, B, SPLITS);
    ntxent_main<<<grid, 256, 0, stream>>>(xn, yn, Ridx, Cidx, cnt, gsum, B);

    dim3 grid2(16, B);
    per_col_loss<<<grid2, 256, 0, stream>>>(xn, yn, gsum, Ridx, Cidx, cnt,
                                            (float*)d_out, B);
}